// Round 3
// baseline (114.724 us; speedup 1.0000x reference)
//
#include <hip/hip_runtime.h>

// Problem constants (match reference)
#define BB 2
#define NN 131072
#define MM 512
#define GG 20
#define VV (GG * GG * GG)      // 8000
#define NBLK 128               // blocks per batch
#define TOTAL_BLOCKS (NBLK * BB)
#define MAXSLOTS 1024

// Workspace layout:
//   0      partialMin : B*NBLK*3 floats (3072 B) -- written by K1 blocks
//   3072   minVals    : B*3 floats (24 B)        -- written by K1 last block
//   3200   sflat      : B*M ints (4096 B)        -- written by K1 last block
//   8192   Z-region (zeroed by the single tiny memset node):
//   8192     done1, done2 : 2 uints
//   8200     counters     : B ints
//   8448     slotmap      : B*V ints (64000 B)   0=unclaimed, else slot+1
//   72448    sums         : B*MAXSLOTS*10 floats (81920 B)
#define OFF_PARTIAL 0
#define OFF_MINV    3072
#define OFF_SFLAT   3200
#define OFF_Z       8192
#define OFF_DONE1   8192
#define OFF_DONE2   8196
#define OFF_CNT     8200
#define OFF_SLOTMAP 8448
#define OFF_SUMS    72448
#define ZBYTES      (256 + 64000 + 81920)   // 146176

__device__ __forceinline__ int vox_coord(float p, float mn) {
    int i = (int)floorf((p - mn) * 2.0f);   // *2 == /0.5 (exact pow2)
    return min(max(i, 0), GG - 1);
}

// ---- K1: per-block min partials; last block reduces + marks ------------
__global__ __launch_bounds__(256) void vox_k1(const float* __restrict__ x,
                                              const int* __restrict__ sidx,
                                              char* __restrict__ ws) {
    const int b = blockIdx.y;
    const int tid = blockIdx.x * 256 + threadIdx.x;   // 0..32767 per batch

    // exactly one group of 3 float4 (= 4 points) per thread
    const float4* xb = (const float4*)(x + (size_t)b * NN * 3);
    float4 f0 = xb[3 * tid + 0];
    float4 f1 = xb[3 * tid + 1];
    float4 f2 = xb[3 * tid + 2];
    float mx = fminf(fminf(f0.x, f0.w), fminf(f1.z, f2.y));
    float my = fminf(fminf(f0.y, f1.x), fminf(f1.w, f2.z));
    float mz = fminf(fminf(f0.z, f1.y), fminf(f2.x, f2.w));

    // wave-64 reduce
    for (int off = 32; off > 0; off >>= 1) {
        mx = fminf(mx, __shfl_down(mx, off, 64));
        my = fminf(my, __shfl_down(my, off, 64));
        mz = fminf(mz, __shfl_down(mz, off, 64));
    }
    __shared__ float lmin[4][3];
    int wave = threadIdx.x >> 6;
    if ((threadIdx.x & 63) == 0) {
        lmin[wave][0] = mx; lmin[wave][1] = my; lmin[wave][2] = mz;
    }
    __syncthreads();
    if (threadIdx.x == 0) {
        float* pm = (float*)(ws + OFF_PARTIAL) + (b * NBLK + blockIdx.x) * 3;
        pm[0] = fminf(fminf(lmin[0][0], lmin[1][0]), fminf(lmin[2][0], lmin[3][0]));
        pm[1] = fminf(fminf(lmin[0][1], lmin[1][1]), fminf(lmin[2][1], lmin[3][1]));
        pm[2] = fminf(fminf(lmin[0][2], lmin[1][2]), fminf(lmin[2][2], lmin[3][2]));
    }

    // ---- last-block-done: winner reduces partials + marks samples ----
    __shared__ int isLast;
    __syncthreads();   // partial store issued before we count this block done
    if (threadIdx.x == 0) {
        unsigned ret = __hip_atomic_fetch_add(
            (unsigned*)(ws + OFF_DONE1), 1u,
            __ATOMIC_ACQ_REL, __HIP_MEMORY_SCOPE_AGENT);
        isLast = (ret == (unsigned)(TOTAL_BLOCKS - 1));
    }
    __syncthreads();
    if (!isLast) return;

    // winner block only (256 threads)
    __shared__ float smin[BB][3];
    if (threadIdx.x < BB * 3) {
        int bb = threadIdx.x / 3, axis = threadIdx.x % 3;
        const float* pm = (const float*)(ws + OFF_PARTIAL);
        float m = 1e30f;
        for (int i = 0; i < NBLK; ++i)
            m = fminf(m, pm[(bb * NBLK + i) * 3 + axis]);
        smin[bb][axis] = m;
        ((float*)(ws + OFF_MINV))[bb * 3 + axis] = m;
    }
    __syncthreads();

    int* sflat = (int*)(ws + OFF_SFLAT);
    int* slotmap = (int*)(ws + OFF_SLOTMAP);
    int* counters = (int*)(ws + OFF_CNT);
    for (int s = threadIdx.x; s < BB * MM; s += 256) {
        int sb = s >> 9;   // s / M
        int pi = sidx[s];
        const float* p = x + ((size_t)sb * NN + pi) * 3;
        int ix = vox_coord(p[0], smin[sb][0]);
        int iy = vox_coord(p[1], smin[sb][1]);
        int iz = vox_coord(p[2], smin[sb][2]);
        int flat = (ix * GG + iy) * GG + iz;
        sflat[s] = flat;
        int old = atomicCAS(&slotmap[sb * VV + flat], 0, -1);
        if (old == 0) {
            int sl = atomicAdd(&counters[sb], 1);
            slotmap[sb * VV + flat] = sl + 1;
        }
    }
}

// ---- K2: accumulate flagged voxels; last block finalizes ---------------
// sums per (b,slot): [cnt, sx, sy, sz, sxx, sxy, sxz, syy, syz, szz]
__global__ __launch_bounds__(256) void vox_k2(const float* __restrict__ x,
                                              char* __restrict__ ws,
                                              float* __restrict__ out) {
    const int b = blockIdx.y;
    const int tid = blockIdx.x * 256 + threadIdx.x;   // 0..32767 per batch
    const float* mv = (const float*)(ws + OFF_MINV) + b * 3;
    const float mnx = mv[0], mny = mv[1], mnz = mv[2];
    const int* slotmap = (const int*)(ws + OFF_SLOTMAP) + b * VV;
    float* sums = (float*)(ws + OFF_SUMS) + (size_t)b * MAXSLOTS * 10;

    const float4* xb = (const float4*)(x + (size_t)b * NN * 3);
    float4 f0 = xb[3 * tid + 0];
    float4 f1 = xb[3 * tid + 1];
    float4 f2 = xb[3 * tid + 2];
    float px[4] = {f0.x, f0.w, f1.z, f2.y};
    float py[4] = {f0.y, f1.x, f1.w, f2.z};
    float pz[4] = {f0.z, f1.y, f2.x, f2.w};
#pragma unroll
    for (int k = 0; k < 4; ++k) {
        int ix = vox_coord(px[k], mnx);
        int iy = vox_coord(py[k], mny);
        int iz = vox_coord(pz[k], mnz);
        int slot = slotmap[(ix * GG + iy) * GG + iz];
        if (slot > 0) {
            float* s = sums + (size_t)(slot - 1) * 10;
            atomicAdd(s + 0, 1.0f);
            atomicAdd(s + 1, px[k]);
            atomicAdd(s + 2, py[k]);
            atomicAdd(s + 3, pz[k]);
            atomicAdd(s + 4, px[k] * px[k]);
            atomicAdd(s + 5, px[k] * py[k]);
            atomicAdd(s + 6, px[k] * pz[k]);
            atomicAdd(s + 7, py[k] * py[k]);
            atomicAdd(s + 8, py[k] * pz[k]);
            atomicAdd(s + 9, pz[k] * pz[k]);
        }
    }

    // ---- last-block-done: winner finalizes the 1024 outputs ----
    __shared__ int isLast;
    __syncthreads();
    if (threadIdx.x == 0) {
        unsigned ret = __hip_atomic_fetch_add(
            (unsigned*)(ws + OFF_DONE2), 1u,
            __ATOMIC_ACQ_REL, __HIP_MEMORY_SCOPE_AGENT);
        isLast = (ret == (unsigned)(TOTAL_BLOCKS - 1));
    }
    __syncthreads();
    if (!isLast) return;

    const int* sflat = (const int*)(ws + OFF_SFLAT);
    const int* slotmapAll = (const int*)(ws + OFF_SLOTMAP);
    const float* sumsAll = (const float*)(ws + OFF_SUMS);
    for (int t = threadIdx.x; t < BB * MM; t += 256) {
        int tb = t >> 9;
        int flat = sflat[t];
        int slot = slotmapAll[tb * VV + flat] - 1;
        const float* s = sumsAll + ((size_t)tb * MAXSLOTS + slot) * 10;
        float cnt = s[0];
        float inv = 1.0f / fmaxf(cnt, 1.0f);
        float mx = s[1] * inv, my = s[2] * inv, mz = s[3] * inv;
        float cxx = s[4] * inv - mx * mx;
        float cxy = s[5] * inv - mx * my;
        float cxz = s[6] * inv - mx * mz;
        float cyy = s[7] * inv - my * my;
        float cyz = s[8] * inv - my * mz;
        float czz = s[9] * inv - mz * mz;
        float* o = out + (size_t)t * 12;
        o[0] = mx;  o[1] = my;  o[2] = mz;
        o[3] = cxx; o[4] = cxy; o[5] = cxz;
        o[6] = cxy; o[7] = cyy; o[8] = cyz;
        o[9] = cxz; o[10] = cyz; o[11] = czz;
    }
}

extern "C" void kernel_launch(void* const* d_in, const int* in_sizes, int n_in,
                              void* d_out, int out_size, void* d_ws, size_t ws_size,
                              hipStream_t stream) {
    const float* x = (const float*)d_in[0];   // (B, N, 3) fp32
    const int* sidx = (const int*)d_in[1];    // (B, M) int32
    float* out = (float*)d_out;               // (B, M, 12) fp32
    char* ws = (char*)d_ws;

    hipMemsetAsync(ws + OFF_Z, 0, ZBYTES, stream);                 // 146 KB
    vox_k1<<<dim3(NBLK, BB), 256, 0, stream>>>(x, sidx, ws);
    vox_k2<<<dim3(NBLK, BB), 256, 0, stream>>>(x, ws, out);
}